// Round 4
// baseline (327.637 us; speedup 1.0000x reference)
//
#include <hip/hip_runtime.h>

typedef __attribute__((ext_vector_type(8)))  short short8;   // 8 bf16 (4 VGPRs)
typedef __attribute__((ext_vector_type(16))) float f32x16;   // 32x32 MFMA acc
typedef unsigned short ushort_t;
typedef unsigned int uint32;
typedef unsigned long long uint64;

#define NROWS 8192
#define NCODE 8192
#define DIM   512

// ---------------- d_out layout (floats) ----------------
#define OUT_Q      0
#define OUT_LOSS   4194304
#define OUT_IDX    4194305
#define OUT_MIND   4202497
#define OUT_COMMIT 4210689

// ---------------- ws layout (floats) ----------------
#define WS_ENORM  0           // 8192
#define WS_KEYS   8192        // 8192 u64 keys (16384 floats)
#define WS_LPART  147456      // 2048
#define WS_BHI    150528      // 8192*512 bf16
#define WS_BLO    2247680

// ===========================================================================
__device__ inline uint32 bf16_rne(float f) {
    uint32 u = __float_as_uint(f);
    return (u + 0x7FFFu + ((u >> 16) & 1u)) >> 16;
}

// ===========================================================================
// Kernel 1: fused conversion of x and codebook into fragment-ordered bf16
// hi/lo tiles in GLOBAL memory. Tile = 128 rows x 32 k, 8 KB, 8 chunks of
// 1 KB: chunk c = (r32)*2 + k16; lane L holds 8 bf16:
//   row = r32*32 + (L&31), k = k16*16 + (L>>5)*8 + j
// This IS the mfma_32x32x16 A/B fragment order -> one coalesced
// global_load_dwordx4 per fragment in the GEMM (no LDS needed at all).
// Also inits the per-row argmin u64 keys.
__global__ __launch_bounds__(256) void conv_kernel(const float* __restrict__ x,
                                                   const float* __restrict__ cb,
                                                   ushort_t* __restrict__ ahi,
                                                   ushort_t* __restrict__ alo,
                                                   ushort_t* __restrict__ bhi,
                                                   ushort_t* __restrict__ blo,
                                                   float* __restrict__ enorm,
                                                   uint64* __restrict__ keys) {
    int gid  = blockIdx.x * 256 + threadIdx.x;   // 0..1048575
    if (gid < NROWS) keys[gid] = 0xFFFFFFFFFFFFFFFFull;
    bool isA = gid < 524288;
    int g    = isA ? gid : gid - 524288;
    int row  = g >> 6;
    int lane = g & 63;
    int k0   = lane * 8;
    const float* src = (isA ? x : cb) + (size_t)row * DIM + k0;
    float v[8];
    *(float4*)&v[0] = *(const float4*)src;
    *(float4*)&v[4] = *(const float4*)(src + 4);
    float s = 0.0f;
    uint32 h[8], l[8];
    #pragma unroll
    for (int i = 0; i < 8; ++i) {
        s += v[i] * v[i];
        h[i] = bf16_rne(v[i]);
        float hf = __uint_as_float(h[i] << 16);
        l[i] = bf16_rne(v[i] - hf);
    }
    // fragment-ordered offset
    int tile = (row >> 7) * 16 + (k0 >> 5);
    int rp = row & 127, kp = k0 & 31;
    int c  = (rp >> 5) * 2 + (kp >> 4);
    int L  = (rp & 31) + (((kp >> 3) & 1) << 5);
    size_t off = (size_t)tile * 4096 + c * 512 + L * 8;   // ushort units
    uint4 ph, pl;
    ph.x = h[0] | (h[1] << 16); ph.y = h[2] | (h[3] << 16);
    ph.z = h[4] | (h[5] << 16); ph.w = h[6] | (h[7] << 16);
    pl.x = l[0] | (l[1] << 16); pl.y = l[2] | (l[3] << 16);
    pl.z = l[4] | (l[5] << 16); pl.w = l[6] | (l[7] << 16);
    if (isA) {
        *(uint4*)(ahi + off) = ph;
        *(uint4*)(alo + off) = pl;
    } else {
        *(uint4*)(bhi + off) = ph;
        *(uint4*)(blo + off) = pl;
        #pragma unroll
        for (int o = 32; o > 0; o >>= 1) s += __shfl_down(s, o);
        if (lane == 0) enorm[row] = s;
    }
}

// ===========================================================================
// Kernel 2 (R4): barrier-free, LDS-free streaming MFMA distance-GEMM.
// Rationale: R0/R1/R3 (three different barrier-locked LDS schedules) were
// all invariant at 51% MfmaUtil -- barrier lockstep makes LDS time and MFMA
// time SUM. Here fragments stream global->register (fragment-ordered layout,
// one coalesced dwordx4 per frag); L1/L2 provide the cross-wave sharing LDS
// used to. No s_barrier / lgkmcnt in the loop; waves fully self-paced.
//   Block: 256 thr, 4 waves stacked by row. Wave tile 64 x 128 (acc[2][4]).
//   Block tile: 256 rows x 512 cols; inner: ct(4) x k16(32) = 128 steps.
//   Grid 512 = 32 row-blocks x 16 col-slices, XCD-chunked by row so the
//   2 MB A row-slice stays L2-resident per XCD.
// Argmin: exact. Per ct: in-thread min over tj, 32-lane shuffle reduce
// (full 32-bit d + min-index tie-break), then one u64 atomicMin per row
// with key = sortable(d)<<32 | col. No argmin state in the K-loop.
struct Frag { short8 ah[2]; short8 al[2]; short8 bh[4]; short8 bl[4]; };

__global__ __launch_bounds__(256, 2) void vq_mfma_kernel(
        const ushort_t* __restrict__ ahi, const ushort_t* __restrict__ alo,
        const ushort_t* __restrict__ bhi, const ushort_t* __restrict__ blo,
        const float* __restrict__ enorm, uint64* __restrict__ keys) {
    const int tid  = threadIdx.x;            // 0..255
    const int wave = tid >> 6, lane = tid & 63;
    const int l31  = lane & 31, half = lane >> 5;
    const int q   = blockIdx.x;
    const int t   = q >> 3;
    const int bx  = (q & 7) * 4 + (t >> 4);  // 0..31 (256-row block), XCD=q&7
    const int by  = t & 15;                  // 0..15 (512-col slice)
    const int r32 = bx * 8 + wave * 2;       // wave's first 32-row tile
    const int l8  = lane * 8;

    f32x16 acc[2][4];
    #pragma unroll
    for (int i = 0; i < 2; ++i)
        #pragma unroll
        for (int j = 0; j < 4; ++j)
            #pragma unroll
            for (int r = 0; r < 16; ++r) acc[i][j][r] = 0.0f;

    // fragment offset in the conv layout (rt = 32-row/col tile, kk = k16)
    auto FOFF = [&](int rt, int kk) -> size_t {
        return ((size_t)((rt >> 2) * 16 + (kk >> 1))) * 4096
             + (size_t)(((rt & 3) * 2 + (kk & 1)) * 512) + l8;
    };

#define LOADF(F, nn) do {                                                     \
    const int ct_ = (nn) >> 5, kk_ = (nn) & 31;                               \
    (F).ah[0] = *(const short8*)&ahi[FOFF(r32,     kk_)];                     \
    (F).ah[1] = *(const short8*)&ahi[FOFF(r32 + 1, kk_)];                     \
    (F).al[0] = *(const short8*)&alo[FOFF(r32,     kk_)];                     \
    (F).al[1] = *(const short8*)&alo[FOFF(r32 + 1, kk_)];                     \
    _Pragma("unroll")                                                         \
    for (int tj = 0; tj < 4; ++tj) {                                          \
        const int c32 = by * 16 + ct_ * 4 + tj;                               \
        (F).bh[tj] = *(const short8*)&bhi[FOFF(c32, kk_)];                    \
        (F).bl[tj] = *(const short8*)&blo[FOFF(c32, kk_)];                    \
    }                                                                         \
} while (0)

#define MFMA8(A, B) do {                                                      \
    __builtin_amdgcn_s_setprio(1);                                            \
    _Pragma("unroll")                                                         \
    for (int ti = 0; ti < 2; ++ti)                                            \
        _Pragma("unroll")                                                     \
        for (int tj = 0; tj < 4; ++tj)                                        \
            acc[ti][tj] = __builtin_amdgcn_mfma_f32_32x32x16_bf16(            \
                (A)[ti], (B)[tj], acc[ti][tj], 0, 0, 0);                      \
    __builtin_amdgcn_s_setprio(0);                                            \
} while (0)

#define BODY(nn, CUR, NXT) do {                                               \
    if ((nn) + 1 < 128) LOADF(NXT, (nn) + 1);                                 \
    MFMA8(CUR.ah, CUR.bh);                                                    \
    MFMA8(CUR.ah, CUR.bl);                                                    \
    MFMA8(CUR.al, CUR.bh);                                                    \
    if (((nn) & 31) == 31) {                                                  \
        const int ct_ = (nn) >> 5;                                            \
        const int colbase = by * 512 + ct_ * 128;                             \
        float en[4];                                                          \
        _Pragma("unroll")                                                     \
        for (int tj = 0; tj < 4; ++tj) en[tj] = enorm[colbase + tj*32 + l31]; \
        _Pragma("unroll")                                                     \
        for (int ti = 0; ti < 2; ++ti)                                        \
            _Pragma("unroll")                                                 \
            for (int r = 0; r < 16; ++r) {                                    \
                float bd = 3.4e38f; int bc = 0;                               \
                _Pragma("unroll")                                             \
                for (int tj = 0; tj < 4; ++tj) {                              \
                    float d = en[tj] - 2.0f * acc[ti][tj][r];                 \
                    int ci = colbase + tj * 32 + l31;                         \
                    if (d < bd) { bd = d; bc = ci; }                          \
                }                                                             \
                _Pragma("unroll")                                             \
                for (int m = 1; m < 32; m <<= 1) {                            \
                    float d2 = __shfl_xor(bd, m);                             \
                    int   c2 = __shfl_xor(bc, m);                             \
                    if (d2 < bd || (d2 == bd && c2 < bc)) { bd = d2; bc = c2;}\
                }                                                             \
                if (l31 == 0) {                                               \
                    int row = bx * 256 + wave * 64 + ti * 32                  \
                            + (r & 3) + 8 * (r >> 2) + 4 * half;              \
                    uint32 u  = __float_as_uint(bd);                          \
                    uint32 su = u ^ (0x80000000u | (uint32)((int)u >> 31));   \
                    atomicMin(&keys[row], ((uint64)su << 32) | (uint32)bc);   \
                }                                                             \
            }                                                                 \
        _Pragma("unroll")                                                     \
        for (int i = 0; i < 2; ++i)                                           \
            _Pragma("unroll")                                                 \
            for (int j = 0; j < 4; ++j)                                       \
                _Pragma("unroll")                                             \
                for (int r = 0; r < 16; ++r) acc[i][j][r] = 0.0f;             \
    }                                                                         \
} while (0)

    Frag Fa, Fb;
    LOADF(Fa, 0);
    for (int n = 0; n < 128; n += 2) {
        BODY(n, Fa, Fb);
        BODY(n + 1, Fb, Fa);
    }
#undef LOADF
#undef MFMA8
#undef BODY
}

// ===========================================================================
// Kernel 3: read per-row u64 key -> idx, gather codebook row,
// exact fp32 ||x-e||^2 -> min_distances + loss partials. One 64-lane group/row.
__global__ __launch_bounds__(256) void finish_kernel(const float* __restrict__ x,
                                                     const float* __restrict__ cb,
                                                     const uint64* __restrict__ keys,
                                                     float* __restrict__ out_idx,
                                                     float* __restrict__ qout,
                                                     float* __restrict__ out_mind,
                                                     float* __restrict__ lpart) {
    __shared__ float sred[4];
    int row  = blockIdx.x * 4 + (threadIdx.x >> 6);
    int lane = threadIdx.x & 63;

    int idx = (int)(uint32)(keys[row] & 0xFFFFFFFFull);
    if (lane == 0) out_idx[row] = (float)idx;

    const float4* e4 = (const float4*)(cb + (size_t)idx * DIM);
    const float4* x4 = (const float4*)(x + (size_t)row * DIM);
    float4* q4 = (float4*)(qout + (size_t)row * DIM);
    float s = 0.0f;
    #pragma unroll
    for (int u = 0; u < 2; ++u) {
        float4 e  = e4[lane + u * 64];
        float4 xv = x4[lane + u * 64];
        q4[lane + u * 64] = e;
        float dx = xv.x - e.x, dy = xv.y - e.y, dz = xv.z - e.z, dw = xv.w - e.w;
        s += dx * dx + dy * dy + dz * dz + dw * dw;
    }
    #pragma unroll
    for (int o = 32; o > 0; o >>= 1) s += __shfl_down(s, o);
    if (lane == 0) { sred[threadIdx.x >> 6] = s; out_mind[row] = s; }
    __syncthreads();
    if (threadIdx.x == 0) lpart[blockIdx.x] = sred[0] + sred[1] + sred[2] + sred[3];
}

// ===========================================================================
// Kernel 4: final loss. loss_vq == loss_commit numerically => loss = 1.25*commit
__global__ __launch_bounds__(256) void loss_kernel(const float* __restrict__ lpart,
                                                   float* __restrict__ out_loss,
                                                   float* __restrict__ out_commit) {
    __shared__ float sm[256];
    float s = 0.0f;
    for (int i = threadIdx.x; i < 2048; i += 256) s += lpart[i];
    sm[threadIdx.x] = s;
    __syncthreads();
    #pragma unroll
    for (int o = 128; o > 0; o >>= 1) {
        if (threadIdx.x < o) sm[threadIdx.x] += sm[threadIdx.x + o];
        __syncthreads();
    }
    if (threadIdx.x == 0) {
        *out_commit = sm[0];
        *out_loss   = 1.25f * sm[0];
    }
}

// ===========================================================================
extern "C" void kernel_launch(void* const* d_in, const int* in_sizes, int n_in,
                              void* d_out, int out_size, void* d_ws, size_t ws_size,
                              hipStream_t stream) {
    const float* x  = (const float*)d_in[0];
    const float* cb = (const float*)d_in[1];
    float* out = (float*)d_out;
    float* ws  = (float*)d_ws;

    // A hi/lo staged in the quantized-output region (rewritten by finish_kernel)
    ushort_t* ahi = (ushort_t*)d_out;
    ushort_t* alo = (ushort_t*)d_out + 4194304;
    ushort_t* bhi = (ushort_t*)(ws + WS_BHI);
    ushort_t* blo = (ushort_t*)(ws + WS_BLO);
    float*  enorm = ws + WS_ENORM;
    uint64* keys  = (uint64*)(ws + WS_KEYS);
    float*  lpart = ws + WS_LPART;

    conv_kernel<<<4096, 256, 0, stream>>>(x, cb, ahi, alo, bhi, blo, enorm, keys);
    vq_mfma_kernel<<<512, 256, 0, stream>>>(ahi, alo, bhi, blo, enorm, keys);
    finish_kernel<<<NROWS / 4, 256, 0, stream>>>(x, cb, keys,
                                                 out + OUT_IDX, out + OUT_Q,
                                                 out + OUT_MIND, lpart);
    loss_kernel<<<1, 256, 0, stream>>>(lpart, out + OUT_LOSS, out + OUT_COMMIT);
}